// Round 1
// baseline (620.785 us; speedup 1.0000x reference)
//
#include <hip/hip_runtime.h>
#include <math.h>

#define B_ 4
#define C_ 128
#define H_ 256
#define W_ 256
#define NPIX (H_*W_)
#define HEADS_ 4

typedef unsigned int uint;
typedef unsigned short ushort;
typedef __attribute__((ext_vector_type(8))) __bf16 bf16x8;
typedef __attribute__((ext_vector_type(4))) float f32x4;

__device__ __forceinline__ ushort f2bf(float f){
    uint u = __builtin_bit_cast(uint, f);
    u += 0x7FFFu + ((u>>16)&1u);        // round-to-nearest-even
    return (ushort)(u>>16);
}
__device__ __forceinline__ float bf2f(ushort h){
    uint u = ((uint)h)<<16;
    return __builtin_bit_cast(float, u);
}
__device__ __forceinline__ int swz3(int i){ return (i ^ (i>>3)) & 7; }

// ---------------------------------------------------------------------------
// K1: S[b] = x_b^T x_b  (128x128 per batch), bf16 MFMA syrk, atomicAdd reduce.
// xT LDS tile: [128 ch][128 rows] bf16, 256B rows, 16B-block XOR swizzle.
// ---------------------------------------------------------------------------
__global__ __launch_bounds__(256) void k1_syrk(const float* __restrict__ x, float* __restrict__ S){
    __shared__ __align__(16) char sm[128*256];
    int blk = blockIdx.x;
    int b = blk >> 7;          // 128 chunks/batch
    int chunk = blk & 127;     // 512 rows per chunk
    long base = ((long)b*NPIX + (long)chunk*512) * C_;
    int t = threadIdx.x;
    int lane = t & 63;
    int w = t >> 6;
    int m0 = (w>>1)*64, n0 = (w&1)*64;

    f32x4 acc[4][4];
    #pragma unroll
    for(int i=0;i<4;i++)
        #pragma unroll
        for(int j=0;j<4;j++) acc[i][j] = {0.f,0.f,0.f,0.f};

    for(int tile=0; tile<4; ++tile){
        // stage 128 rows -> transposed swizzled xT
        {
            int rp = (t>>5)*2;
            int c0 = (t&31)*4;
            const float* xp = x + base + (long)tile*128*C_;
            #pragma unroll
            for(int p=0;p<8;p++){
                int r = p*16 + rp;
                float4 a0 = *(const float4*)(xp + r*C_ + c0);
                float4 a1 = *(const float4*)(xp + (r+1)*C_ + c0);
                float v0[4] = {a0.x,a0.y,a0.z,a0.w};
                float v1[4] = {a1.x,a1.y,a1.z,a1.w};
                #pragma unroll
                for(int i=0;i<4;i++){
                    int cch = c0+i;
                    uint pk = (uint)f2bf(v0[i]) | ((uint)f2bf(v1[i])<<16);
                    *(uint*)(sm + cch*256 + ((2*r) ^ (swz3(cch)<<4))) = pk;
                }
            }
        }
        __syncthreads();
        #pragma unroll
        for(int kk=0;kk<4;kk++){
            int rb = kk*32 + (lane>>4)*8;
            bf16x8 A[4], Bf[4];
            #pragma unroll
            for(int i=0;i<4;i++){
                int cch = m0 + i*16 + (lane&15);
                A[i] = *(const bf16x8*)(sm + cch*256 + ((2*rb) ^ (swz3(cch)<<4)));
            }
            #pragma unroll
            for(int j=0;j<4;j++){
                int cch = n0 + j*16 + (lane&15);
                Bf[j] = *(const bf16x8*)(sm + cch*256 + ((2*rb) ^ (swz3(cch)<<4)));
            }
            #pragma unroll
            for(int i=0;i<4;i++)
                #pragma unroll
                for(int j=0;j<4;j++)
                    acc[i][j] = __builtin_amdgcn_mfma_f32_16x16x32_bf16(A[i], Bf[j], acc[i][j], 0,0,0);
        }
        __syncthreads();
    }
    float* Sb = S + b*C_*C_;
    int rq = (lane>>4)*4;
    int cc = lane&15;
    #pragma unroll
    for(int i=0;i<4;i++)
        #pragma unroll
        for(int j=0;j<4;j++)
            #pragma unroll
            for(int rg=0;rg<4;rg++){
                int row = m0 + i*16 + rq + rg;
                int col = n0 + j*16 + cc;
                atomicAdd(&Sb[row*C_ + col], acc[i][j][rg]);
            }
}

// ---------------------------------------------------------------------------
// K2: v_inp = x @ Wv  -> ws (bf16, [b][n][c]); LDS-bounce for coalesced store.
// ---------------------------------------------------------------------------
__global__ __launch_bounds__(256) void k2_vinp(const float* __restrict__ x, const float* __restrict__ Wv,
                                               ushort* __restrict__ vout){
    __shared__ __align__(16) char smx[128*256];
    __shared__ __align__(16) char smw[128*256];
    int blk = blockIdx.x;
    int b = blk >> 9; int tileI = blk & 511;
    long rowbase = (long)b*NPIX + (long)tileI*128;
    int t = threadIdx.x, lane = t&63, w = t>>6;
    int m0 = (w>>1)*64, n0 = (w&1)*64;

    // stage WvT: Wv[in][out] -> smw[out][in]
    {
        #pragma unroll
        for(int p=0;p<16;p++){
            int in = p*8 + (t>>5);
            int o0 = (t&31)*4;
            float4 wv = *(const float4*)(Wv + in*C_ + o0);
            float vv[4]={wv.x,wv.y,wv.z,wv.w};
            #pragma unroll
            for(int i=0;i<4;i++){
                int o = o0+i;
                *(ushort*)(smw + o*256 + ((2*in) ^ (swz3(o)<<4))) = f2bf(vv[i]);
            }
        }
    }
    // stage x tile row-major
    {
        const float* xp = x + rowbase*C_;
        #pragma unroll
        for(int p=0;p<16;p++){
            int r = p*8 + (t>>5);
            int c0 = (t&31)*4;
            float4 a = *(const float4*)(xp + r*C_ + c0);
            uint2 pk;
            pk.x = (uint)f2bf(a.x) | ((uint)f2bf(a.y)<<16);
            pk.y = (uint)f2bf(a.z) | ((uint)f2bf(a.w)<<16);
            *(uint2*)(smx + r*256 + ((2*c0) ^ (swz3(r)<<4))) = pk;
        }
    }
    __syncthreads();

    f32x4 acc[4][4];
    #pragma unroll
    for(int i=0;i<4;i++)
        #pragma unroll
        for(int j=0;j<4;j++) acc[i][j] = {0.f,0.f,0.f,0.f};

    #pragma unroll
    for(int kk=0;kk<4;kk++){
        int kb = kk*32 + (lane>>4)*8;
        bf16x8 A[4], Bf[4];
        #pragma unroll
        for(int i=0;i<4;i++){
            int r = m0 + i*16 + (lane&15);
            A[i] = *(const bf16x8*)(smx + r*256 + ((2*kb) ^ (swz3(r)<<4)));
        }
        #pragma unroll
        for(int j=0;j<4;j++){
            int o = n0 + j*16 + (lane&15);
            Bf[j] = *(const bf16x8*)(smw + o*256 + ((2*kb) ^ (swz3(o)<<4)));
        }
        #pragma unroll
        for(int i=0;i<4;i++)
            #pragma unroll
            for(int j=0;j<4;j++)
                acc[i][j] = __builtin_amdgcn_mfma_f32_16x16x32_bf16(A[i], Bf[j], acc[i][j], 0,0,0);
    }
    __syncthreads();
    // bounce into smx (bf16, swizzled row-major)
    {
        int rq = (lane>>4)*4, cc = lane&15;
        #pragma unroll
        for(int i=0;i<4;i++)
            #pragma unroll
            for(int j=0;j<4;j++)
                #pragma unroll
                for(int rg=0;rg<4;rg++){
                    int row = m0 + i*16 + rq + rg;
                    int col = n0 + j*16 + cc;
                    *(ushort*)(smx + row*256 + ((2*col) ^ (swz3(row)<<4))) = f2bf(acc[i][j][rg]);
                }
    }
    __syncthreads();
    {
        ushort* vp = vout + rowbase*C_;
        #pragma unroll
        for(int p=0;p<8;p++){
            int idx = p*256 + t;     // 2048 16B-units
            int row = idx >> 4;
            int ub  = idx & 15;
            uint4 d = *(const uint4*)(smx + row*256 + ((ub*16) ^ (swz3(row)<<4)));
            *(uint4*)(vp + row*C_ + ub*8) = d;
        }
    }
}

// ---------------------------------------------------------------------------
// K3: attention from S;  WeffT[b][c][he] = sum_d attn[b,h,d,e] Wp[(h,d),c]
// ---------------------------------------------------------------------------
__global__ __launch_bounds__(1024) void k3_attn(const float* __restrict__ S, const float* __restrict__ Wq,
                                                const float* __restrict__ Wk, const float* __restrict__ rescale,
                                                const float* __restrict__ Wp, ushort* __restrict__ WeffT){
    __shared__ float sT[C_*C_];
    __shared__ float sG[HEADS_*32*32];
    __shared__ float sNq[C_], sNk[C_];
    int b = blockIdx.x;
    int t = threadIdx.x;
    const float* Sb = S + b*C_*C_;
    int c = t >> 3;
    int e0 = (t & 7) * 16;
    // TQ = S@Wq
    {
        float a[16];
        #pragma unroll
        for(int j=0;j<16;j++) a[j]=0.f;
        for(int c2=0;c2<C_;c2++){
            float s = Sb[c*C_ + c2];
            const float* wq = Wq + c2*C_ + e0;
            #pragma unroll
            for(int j=0;j<16;j++) a[j] += s * wq[j];
        }
        #pragma unroll
        for(int j=0;j<16;j++) sT[c*C_ + e0 + j] = a[j];
    }
    __syncthreads();
    if(t < C_){
        float s = 0.f;
        for(int cc=0;cc<C_;cc++) s += Wq[cc*C_ + t] * sT[cc*C_ + t];
        sNq[t] = fmaxf(sqrtf(fmaxf(s, 0.f)), 1e-12f);
    }
    {
        #pragma unroll
        for(int q=0;q<4;q++){
            int o = q*1024 + t;
            int h = o >> 10, d = (o>>5)&31, e = o&31;
            float s = 0.f;
            for(int cc=0;cc<C_;cc++) s += Wk[cc*C_ + h*32 + d] * sT[cc*C_ + h*32 + e];
            sG[o] = s;
        }
    }
    __syncthreads();
    // U = S@Wk (overwrite sT)
    {
        float a[16];
        #pragma unroll
        for(int j=0;j<16;j++) a[j]=0.f;
        for(int c2=0;c2<C_;c2++){
            float s = Sb[c*C_ + c2];
            const float* wk = Wk + c2*C_ + e0;
            #pragma unroll
            for(int j=0;j<16;j++) a[j] += s * wk[j];
        }
        __syncthreads();
        #pragma unroll
        for(int j=0;j<16;j++) sT[c*C_ + e0 + j] = a[j];
    }
    __syncthreads();
    if(t < C_){
        float s = 0.f;
        for(int cc=0;cc<C_;cc++) s += Wk[cc*C_ + t] * sT[cc*C_ + t];
        sNk[t] = fmaxf(sqrtf(fmaxf(s, 0.f)), 1e-12f);
    }
    __syncthreads();
    if(t < C_){
        int h = t >> 5, d = t & 31;
        float rs = rescale[h];
        float inK = 1.f / sNk[h*32 + d];
        float le[32];
        float mx = -1e30f;
        #pragma unroll
        for(int e=0;e<32;e++){
            float l = sG[h*1024 + d*32 + e] * inK / sNq[h*32 + e] * rs;
            le[e] = l;
            mx = fmaxf(mx, l);
        }
        float sum = 0.f;
        #pragma unroll
        for(int e=0;e<32;e++){ le[e] = expf(le[e]-mx); sum += le[e]; }
        float inv = 1.f/sum;
        #pragma unroll
        for(int e=0;e<32;e++) sG[h*1024 + d*32 + e] = le[e]*inv;
    }
    __syncthreads();
    // WeffT
    {
        int hh = e0 >> 5;
        int eb = e0 & 31;
        float wpd[32];
        #pragma unroll
        for(int d=0;d<32;d++) wpd[d] = Wp[(hh*32+d)*C_ + c];
        ushort* wout = WeffT + b*C_*C_ + c*C_ + e0;
        #pragma unroll
        for(int j=0;j<16;j++){
            int e = eb + j;
            float s = 0.f;
            #pragma unroll
            for(int d=0;d<32;d++) s += sG[hh*1024 + d*32 + e] * wpd[d];
            wout[j] = f2bf(s);
        }
    }
}

// ---------------------------------------------------------------------------
// K4a: c1 = gelu(dwconv3x3(v_inp, w1))  (bf16 in/out, fp32 math)
// ---------------------------------------------------------------------------
__global__ __launch_bounds__(256) void k4a_conv1(const ushort* __restrict__ vinp, const float* __restrict__ w1,
                                                 ushort* __restrict__ c1){
    int blk = blockIdx.x;
    int b = blk >> 8; int y = blk & 255;
    int t = threadIdx.x;
    int c0 = (t & 15)*8;
    int xi = t >> 4;
    float wreg[9][8];
    #pragma unroll
    for(int k=0;k<9;k++){
        float4 a = *(const float4*)(w1 + k*C_ + c0);
        float4 bq = *(const float4*)(w1 + k*C_ + c0 + 4);
        wreg[k][0]=a.x; wreg[k][1]=a.y; wreg[k][2]=a.z; wreg[k][3]=a.w;
        wreg[k][4]=bq.x; wreg[k][5]=bq.y; wreg[k][6]=bq.z; wreg[k][7]=bq.w;
    }
    const ushort* vb = vinp + (long)b*NPIX*C_;
    ushort* cb = c1 + (long)b*NPIX*C_;
    for(int p=0;p<16;p++){
        int xx = p*16 + xi;
        float s[8] = {0,0,0,0,0,0,0,0};
        #pragma unroll
        for(int ky=0;ky<3;ky++){
            int yy = y + ky - 1;
            if(yy < 0 || yy >= H_) continue;
            #pragma unroll
            for(int kx=0;kx<3;kx++){
                int xw = xx + kx - 1;
                if(xw < 0 || xw >= W_) continue;
                uint4 vv = *(const uint4*)(vb + ((long)yy*W_ + xw)*C_ + c0);
                const ushort* pv = (const ushort*)&vv;
                #pragma unroll
                for(int i=0;i<8;i++) s[i] += bf2f(pv[i]) * wreg[ky*3+kx][i];
            }
        }
        uint4 o;
        uint op[4];
        #pragma unroll
        for(int i2=0;i2<4;i2++){
            float va = s[i2*2],   ga = 0.5f*va*(1.0f+erff(va*0.70710678118654752f));
            float vb2 = s[i2*2+1], gb = 0.5f*vb2*(1.0f+erff(vb2*0.70710678118654752f));
            op[i2] = (uint)f2bf(ga) | ((uint)f2bf(gb)<<16);
        }
        o.x=op[0]; o.y=op[1]; o.z=op[2]; o.w=op[3];
        *(uint4*)(cb + ((long)y*W_ + xx)*C_ + c0) = o;
    }
}

// ---------------------------------------------------------------------------
// K4b: out = (v_inp .* ilf) @ WeffT_b + bp   (bf16 MFMA, fp32 out)
// ---------------------------------------------------------------------------
__global__ __launch_bounds__(256) void k4b_x1(const ushort* __restrict__ vinp, const float* __restrict__ ilf,
                                              const ushort* __restrict__ WeffT, const float* __restrict__ bp,
                                              float* __restrict__ out){
    __shared__ __align__(16) char smv[128*256];
    __shared__ __align__(16) char smw[128*256];
    int blk = blockIdx.x;
    int b = blk >> 9; int tileI = blk & 511;
    long rowbase = (long)b*NPIX + (long)tileI*128;
    int t = threadIdx.x, lane=t&63, w=t>>6;
    int m0=(w>>1)*64, n0=(w&1)*64;
    // stage WeffT[b] (bf16 row-major [c][he]) -> swizzled LDS
    {
        const ushort* wp = WeffT + b*C_*C_;
        #pragma unroll
        for(int p=0;p<8;p++){
            int idx = p*256 + t;
            int cR = idx >> 4; int ub = idx & 15;
            uint4 d = *(const uint4*)(wp + cR*C_ + ub*8);
            *(uint4*)(smw + cR*256 + ((ub*16) ^ (swz3(cR)<<4))) = d;
        }
    }
    // stage v = v_inp .* ilf
    {
        const ushort* vp = vinp + rowbase*C_;
        const float*  ip = ilf + rowbase*C_;
        #pragma unroll
        for(int p=0;p<8;p++){
            int r = p*16 + (t>>4);
            int c0 = (t&15)*8;
            uint4 vv = *(const uint4*)(vp + r*C_ + c0);
            const ushort* pv = (const ushort*)&vv;
            float4 i0 = *(const float4*)(ip + r*C_ + c0);
            float4 i1 = *(const float4*)(ip + r*C_ + c0 + 4);
            uint4 pk;
            pk.x = (uint)f2bf(bf2f(pv[0])*i0.x) | ((uint)f2bf(bf2f(pv[1])*i0.y)<<16);
            pk.y = (uint)f2bf(bf2f(pv[2])*i0.z) | ((uint)f2bf(bf2f(pv[3])*i0.w)<<16);
            pk.z = (uint)f2bf(bf2f(pv[4])*i1.x) | ((uint)f2bf(bf2f(pv[5])*i1.y)<<16);
            pk.w = (uint)f2bf(bf2f(pv[6])*i1.z) | ((uint)f2bf(bf2f(pv[7])*i1.w)<<16);
            *(uint4*)(smv + r*256 + ((2*c0) ^ (swz3(r)<<4))) = pk;
        }
    }
    __syncthreads();

    f32x4 acc[4][4];
    #pragma unroll
    for(int i=0;i<4;i++)
        #pragma unroll
        for(int j=0;j<4;j++) acc[i][j] = {0.f,0.f,0.f,0.f};

    #pragma unroll
    for(int kk=0;kk<4;kk++){
        int kb = kk*32 + (lane>>4)*8;
        bf16x8 A[4], Bf[4];
        #pragma unroll
        for(int i=0;i<4;i++){
            int r = m0 + i*16 + (lane&15);
            A[i] = *(const bf16x8*)(smv + r*256 + ((2*kb) ^ (swz3(r)<<4)));
        }
        #pragma unroll
        for(int j=0;j<4;j++){
            int o = n0 + j*16 + (lane&15);
            Bf[j] = *(const bf16x8*)(smw + o*256 + ((2*kb) ^ (swz3(o)<<4)));
        }
        #pragma unroll
        for(int i=0;i<4;i++)
            #pragma unroll
            for(int j=0;j<4;j++)
                acc[i][j] = __builtin_amdgcn_mfma_f32_16x16x32_bf16(A[i], Bf[j], acc[i][j], 0,0,0);
    }
    float* op = out + rowbase*C_;
    int rq = (lane>>4)*4, cc = lane&15;
    #pragma unroll
    for(int j=0;j<4;j++){
        int col = n0 + j*16 + cc;
        float bias = bp[col];
        #pragma unroll
        for(int i=0;i<4;i++)
            #pragma unroll
            for(int rg=0;rg<4;rg++){
                int row = m0 + i*16 + rq + rg;
                op[row*C_ + col] = acc[i][j][rg] + bias;
            }
    }
}

// ---------------------------------------------------------------------------
// K4c: out += dwconv3x3(c1, w2)
// ---------------------------------------------------------------------------
__global__ __launch_bounds__(256) void k4c_conv2(const ushort* __restrict__ c1, const float* __restrict__ w2,
                                                 float* __restrict__ out){
    int blk = blockIdx.x;
    int b = blk >> 8; int y = blk & 255;
    int t = threadIdx.x;
    int c0 = (t & 15)*8;
    int xi = t >> 4;
    float wreg[9][8];
    #pragma unroll
    for(int k=0;k<9;k++){
        float4 a = *(const float4*)(w2 + k*C_ + c0);
        float4 bq = *(const float4*)(w2 + k*C_ + c0 + 4);
        wreg[k][0]=a.x; wreg[k][1]=a.y; wreg[k][2]=a.z; wreg[k][3]=a.w;
        wreg[k][4]=bq.x; wreg[k][5]=bq.y; wreg[k][6]=bq.z; wreg[k][7]=bq.w;
    }
    const ushort* cb = c1 + (long)b*NPIX*C_;
    float* ob = out + (long)b*NPIX*C_;
    for(int p=0;p<16;p++){
        int xx = p*16 + xi;
        float s[8] = {0,0,0,0,0,0,0,0};
        #pragma unroll
        for(int ky=0;ky<3;ky++){
            int yy = y + ky - 1;
            if(yy < 0 || yy >= H_) continue;
            #pragma unroll
            for(int kx=0;kx<3;kx++){
                int xw = xx + kx - 1;
                if(xw < 0 || xw >= W_) continue;
                uint4 vv = *(const uint4*)(cb + ((long)yy*W_ + xw)*C_ + c0);
                const ushort* pv = (const ushort*)&vv;
                #pragma unroll
                for(int i=0;i<8;i++) s[i] += bf2f(pv[i]) * wreg[ky*3+kx][i];
            }
        }
        long off = ((long)y*W_ + xx)*C_ + c0;
        float4 o0 = *(const float4*)(ob + off);
        float4 o1 = *(const float4*)(ob + off + 4);
        o0.x += s[0]; o0.y += s[1]; o0.z += s[2]; o0.w += s[3];
        o1.x += s[4]; o1.y += s[5]; o1.z += s[6]; o1.w += s[7];
        *(float4*)(ob + off) = o0;
        *(float4*)(ob + off + 4) = o1;
    }
}

extern "C" void kernel_launch(void* const* d_in, const int* in_sizes, int n_in,
                              void* d_out, int out_size, void* d_ws, size_t ws_size,
                              hipStream_t stream){
    (void)in_sizes; (void)n_in; (void)out_size; (void)ws_size;
    const float* x    = (const float*)d_in[0];
    const float* ilf  = (const float*)d_in[1];
    const float* Wq   = (const float*)d_in[2];
    const float* Wk   = (const float*)d_in[3];
    const float* Wv   = (const float*)d_in[4];
    const float* rsc  = (const float*)d_in[5];
    const float* Wp   = (const float*)d_in[6];
    const float* bp   = (const float*)d_in[7];
    const float* w1   = (const float*)d_in[8];
    const float* w2   = (const float*)d_in[9];
    float* out = (float*)d_out;
    char* ws = (char*)d_ws;

    ushort* vinp  = (ushort*)ws;                       // 4*65536*128 bf16 = 64 MiB
    ushort* c1    = (ushort*)(ws + 67108864);          // 64 MiB
    float*  S     = (float*)(ws + 134217728);          // 256 KiB
    ushort* WeffT = (ushort*)(ws + 134479872);         // 128 KiB

    hipMemsetAsync(S, 0, (size_t)B_*C_*C_*sizeof(float), stream);
    hipLaunchKernelGGL(k1_syrk,  dim3(512),  dim3(256),  0, stream, x, S);
    hipLaunchKernelGGL(k2_vinp,  dim3(2048), dim3(256),  0, stream, x, Wv, vinp);
    hipLaunchKernelGGL(k3_attn,  dim3(4),    dim3(1024), 0, stream, S, Wq, Wk, rsc, Wp, WeffT);
    hipLaunchKernelGGL(k4a_conv1,dim3(1024), dim3(256),  0, stream, vinp, w1, c1);
    hipLaunchKernelGGL(k4b_x1,   dim3(2048), dim3(256),  0, stream, vinp, ilf, WeffT, bp, out);
    hipLaunchKernelGGL(k4c_conv2,dim3(1024), dim3(256),  0, stream, c1, w2, out);
}

// Round 2
// 395.283 us; speedup vs baseline: 1.5705x; 1.5705x over previous
//
#include <hip/hip_runtime.h>
#include <math.h>

#define B_ 4
#define C_ 128
#define H_ 256
#define W_ 256
#define NPIX (H_*W_)
#define HEADS_ 4

typedef unsigned int uint;
typedef unsigned short ushort;
typedef __attribute__((ext_vector_type(8))) __bf16 bf16x8;
typedef __attribute__((ext_vector_type(4))) float f32x4;

__device__ __forceinline__ ushort f2bf(float f){
    uint u = __builtin_bit_cast(uint, f);
    u += 0x7FFFu + ((u>>16)&1u);        // round-to-nearest-even
    return (ushort)(u>>16);
}
__device__ __forceinline__ float bf2f(ushort h){
    uint u = ((uint)h)<<16;
    return __builtin_bit_cast(float, u);
}
__device__ __forceinline__ int swz3(int i){ return (i ^ (i>>3)) & 7; }

// ---------------------------------------------------------------------------
// K1: S[b] = x_b^T x_b  (128x128 per batch), bf16 MFMA syrk, atomicAdd reduce.
// ---------------------------------------------------------------------------
__global__ __launch_bounds__(256) void k1_syrk(const float* __restrict__ x, float* __restrict__ S){
    __shared__ __align__(16) char sm[128*256];
    int blk = blockIdx.x;
    int b = blk >> 7;          // 128 chunks/batch
    int chunk = blk & 127;     // 512 rows per chunk
    long base = ((long)b*NPIX + (long)chunk*512) * C_;
    int t = threadIdx.x;
    int lane = t & 63;
    int w = t >> 6;
    int m0 = (w>>1)*64, n0 = (w&1)*64;

    f32x4 acc[4][4];
    #pragma unroll
    for(int i=0;i<4;i++)
        #pragma unroll
        for(int j=0;j<4;j++) acc[i][j] = {0.f,0.f,0.f,0.f};

    for(int tile=0; tile<4; ++tile){
        {
            int rp = (t>>5)*2;
            int c0 = (t&31)*4;
            const float* xp = x + base + (long)tile*128*C_;
            #pragma unroll
            for(int p=0;p<8;p++){
                int r = p*16 + rp;
                float4 a0 = *(const float4*)(xp + r*C_ + c0);
                float4 a1 = *(const float4*)(xp + (r+1)*C_ + c0);
                float v0[4] = {a0.x,a0.y,a0.z,a0.w};
                float v1[4] = {a1.x,a1.y,a1.z,a1.w};
                #pragma unroll
                for(int i=0;i<4;i++){
                    int cch = c0+i;
                    uint pk = (uint)f2bf(v0[i]) | ((uint)f2bf(v1[i])<<16);
                    *(uint*)(sm + cch*256 + ((2*r) ^ (swz3(cch)<<4))) = pk;
                }
            }
        }
        __syncthreads();
        #pragma unroll
        for(int kk=0;kk<4;kk++){
            int rb = kk*32 + (lane>>4)*8;
            bf16x8 A[4], Bf[4];
            #pragma unroll
            for(int i=0;i<4;i++){
                int cch = m0 + i*16 + (lane&15);
                A[i] = *(const bf16x8*)(sm + cch*256 + ((2*rb) ^ (swz3(cch)<<4)));
            }
            #pragma unroll
            for(int j=0;j<4;j++){
                int cch = n0 + j*16 + (lane&15);
                Bf[j] = *(const bf16x8*)(sm + cch*256 + ((2*rb) ^ (swz3(cch)<<4)));
            }
            #pragma unroll
            for(int i=0;i<4;i++)
                #pragma unroll
                for(int j=0;j<4;j++)
                    acc[i][j] = __builtin_amdgcn_mfma_f32_16x16x32_bf16(A[i], Bf[j], acc[i][j], 0,0,0);
        }
        __syncthreads();
    }
    float* Sb = S + b*C_*C_;
    int rq = (lane>>4)*4;
    int cc = lane&15;
    #pragma unroll
    for(int i=0;i<4;i++)
        #pragma unroll
        for(int j=0;j<4;j++)
            #pragma unroll
            for(int rg=0;rg<4;rg++){
                int row = m0 + i*16 + rq + rg;
                int col = n0 + j*16 + cc;
                atomicAdd(&Sb[row*C_ + col], acc[i][j][rg]);
            }
}

// ---------------------------------------------------------------------------
// K2: v_inp = x @ Wv  -> ws (bf16, [b][n][c]); LDS-bounce for coalesced store.
// ---------------------------------------------------------------------------
__global__ __launch_bounds__(256) void k2_vinp(const float* __restrict__ x, const float* __restrict__ Wv,
                                               ushort* __restrict__ vout){
    __shared__ __align__(16) char smx[128*256];
    __shared__ __align__(16) char smw[128*256];
    int blk = blockIdx.x;
    int b = blk >> 9; int tileI = blk & 511;
    long rowbase = (long)b*NPIX + (long)tileI*128;
    int t = threadIdx.x, lane = t&63, w = t>>6;
    int m0 = (w>>1)*64, n0 = (w&1)*64;

    {
        #pragma unroll
        for(int p=0;p<16;p++){
            int in = p*8 + (t>>5);
            int o0 = (t&31)*4;
            float4 wv = *(const float4*)(Wv + in*C_ + o0);
            float vv[4]={wv.x,wv.y,wv.z,wv.w};
            #pragma unroll
            for(int i=0;i<4;i++){
                int o = o0+i;
                *(ushort*)(smw + o*256 + ((2*in) ^ (swz3(o)<<4))) = f2bf(vv[i]);
            }
        }
    }
    {
        const float* xp = x + rowbase*C_;
        #pragma unroll
        for(int p=0;p<16;p++){
            int r = p*8 + (t>>5);
            int c0 = (t&31)*4;
            float4 a = *(const float4*)(xp + r*C_ + c0);
            uint2 pk;
            pk.x = (uint)f2bf(a.x) | ((uint)f2bf(a.y)<<16);
            pk.y = (uint)f2bf(a.z) | ((uint)f2bf(a.w)<<16);
            *(uint2*)(smx + r*256 + ((2*c0) ^ (swz3(r)<<4))) = pk;
        }
    }
    __syncthreads();

    f32x4 acc[4][4];
    #pragma unroll
    for(int i=0;i<4;i++)
        #pragma unroll
        for(int j=0;j<4;j++) acc[i][j] = {0.f,0.f,0.f,0.f};

    #pragma unroll
    for(int kk=0;kk<4;kk++){
        int kb = kk*32 + (lane>>4)*8;
        bf16x8 A[4], Bf[4];
        #pragma unroll
        for(int i=0;i<4;i++){
            int r = m0 + i*16 + (lane&15);
            A[i] = *(const bf16x8*)(smx + r*256 + ((2*kb) ^ (swz3(r)<<4)));
        }
        #pragma unroll
        for(int j=0;j<4;j++){
            int o = n0 + j*16 + (lane&15);
            Bf[j] = *(const bf16x8*)(smw + o*256 + ((2*kb) ^ (swz3(o)<<4)));
        }
        #pragma unroll
        for(int i=0;i<4;i++)
            #pragma unroll
            for(int j=0;j<4;j++)
                acc[i][j] = __builtin_amdgcn_mfma_f32_16x16x32_bf16(A[i], Bf[j], acc[i][j], 0,0,0);
    }
    __syncthreads();
    {
        int rq = (lane>>4)*4, cc = lane&15;
        #pragma unroll
        for(int i=0;i<4;i++)
            #pragma unroll
            for(int j=0;j<4;j++)
                #pragma unroll
                for(int rg=0;rg<4;rg++){
                    int row = m0 + i*16 + rq + rg;
                    int col = n0 + j*16 + cc;
                    *(ushort*)(smx + row*256 + ((2*col) ^ (swz3(row)<<4))) = f2bf(acc[i][j][rg]);
                }
    }
    __syncthreads();
    {
        ushort* vp = vout + rowbase*C_;
        #pragma unroll
        for(int p=0;p<8;p++){
            int idx = p*256 + t;
            int row = idx >> 4;
            int ub  = idx & 15;
            uint4 d = *(const uint4*)(smx + row*256 + ((ub*16) ^ (swz3(row)<<4)));
            *(uint4*)(vp + row*C_ + ub*8) = d;
        }
    }
}

// ---------------------------------------------------------------------------
// K3a: TQ = S@Wq (stored), U = S@Wk (norm contributions only).
// grid 512 = b*128 + c ; 256 threads: t<128 -> Wq/TQ col, t>=128 -> Wk col.
// ---------------------------------------------------------------------------
__global__ __launch_bounds__(256) void k3a(const float* __restrict__ S, const float* __restrict__ Wq,
                                           const float* __restrict__ Wk, float* __restrict__ TQ,
                                           float* __restrict__ nrm){
    int b = blockIdx.x >> 7, c = blockIdx.x & 127;
    __shared__ float sS[C_];
    int t = threadIdx.x;
    if(t < C_) sS[t] = S[(b*C_+c)*C_ + t];
    __syncthreads();
    const float* Wm = (t < C_) ? Wq : Wk;
    int col = t & (C_-1);
    float acc = 0.f;
    #pragma unroll 4
    for(int c2=0;c2<C_;c2++) acc += sS[c2] * Wm[c2*C_ + col];
    if(t < C_){
        TQ[(b*C_+c)*C_ + col] = acc;
        atomicAdd(&nrm[b*256 + col], Wq[c*C_+col]*acc);
    } else {
        atomicAdd(&nrm[b*256 + C_ + col], Wk[c*C_+col]*acc);
    }
}

// ---------------------------------------------------------------------------
// K3b: per (b,h): G = Wk_h^T TQ_h, scaled softmax, WeffT = attn @ Wp_h.
// grid 16 = b*4 + h ; 256 threads.
// ---------------------------------------------------------------------------
__global__ __launch_bounds__(256) void k3b(const float* __restrict__ TQ, const float* __restrict__ Wk,
                                           const float* __restrict__ rescale, const float* __restrict__ Wp,
                                           const float* __restrict__ nrm, ushort* __restrict__ WeffT){
    int b = blockIdx.x >> 2, h = blockIdx.x & 3;
    int t = threadIdx.x;
    __shared__ float sTQ[C_*32];   // [c][e], later reused as sWp[d][c]
    __shared__ float sWk[C_*32];   // [c][d]
    __shared__ float sG[32*32];    // [d][e]
    __shared__ float sinq[32], sink[32];

    #pragma unroll
    for(int p=0;p<16;p++){
        int idx = p*256 + t;
        int c = idx >> 5, e = idx & 31;
        sTQ[idx] = TQ[(b*C_+c)*C_ + h*32 + e];
        sWk[idx] = Wk[c*C_ + h*32 + e];
    }
    if(t < 32) sinq[t] = 1.f/fmaxf(sqrtf(fmaxf(nrm[b*256 + h*32 + t], 0.f)), 1e-12f);
    else if(t < 64) sink[t-32] = 1.f/fmaxf(sqrtf(fmaxf(nrm[b*256 + C_ + h*32 + (t-32)], 0.f)), 1e-12f);
    __syncthreads();

    float g[4];
    #pragma unroll
    for(int p=0;p<4;p++){
        int idx = p*256 + t;
        int d = idx >> 5, e = idx & 31;
        float a = 0.f;
        #pragma unroll 4
        for(int c=0;c<C_;c++) a += sWk[c*32+d]*sTQ[c*32+e];
        g[p] = a;
    }
    #pragma unroll
    for(int p=0;p<4;p++) sG[p*256 + t] = g[p];
    __syncthreads();

    if(t < 32){
        int d = t;
        float rs = rescale[h] * sink[d];
        float l[32]; float mx = -1e30f;
        #pragma unroll
        for(int e=0;e<32;e++){ l[e] = sG[d*32+e]*rs*sinq[e]; mx = fmaxf(mx, l[e]); }
        float sum = 0.f;
        #pragma unroll
        for(int e=0;e<32;e++){ l[e] = expf(l[e]-mx); sum += l[e]; }
        float inv = 1.f/sum;
        #pragma unroll
        for(int e=0;e<32;e++) sG[d*32+e] = l[e]*inv;
    }
    __syncthreads();

    // reuse sTQ as sWp[d][c]
    #pragma unroll
    for(int p=0;p<16;p++){
        int idx = p*256 + t;
        int d = idx >> 7, c = idx & 127;
        sTQ[idx] = Wp[(h*32+d)*C_ + c];
    }
    __syncthreads();

    #pragma unroll
    for(int p=0;p<16;p++){
        int idx = p*256 + t;
        int c = idx >> 5, e = idx & 31;
        float a = 0.f;
        #pragma unroll
        for(int d=0;d<32;d++) a += sG[d*32+e]*sTQ[d*128+c];
        WeffT[((long)b*C_+c)*C_ + h*32 + e] = f2bf(a);
    }
}

// ---------------------------------------------------------------------------
// K4a: c1 = gelu(dwconv3x3(v_inp, w1))
// ---------------------------------------------------------------------------
__global__ __launch_bounds__(256) void k4a_conv1(const ushort* __restrict__ vinp, const float* __restrict__ w1,
                                                 ushort* __restrict__ c1){
    int blk = blockIdx.x;
    int b = blk >> 8; int y = blk & 255;
    int t = threadIdx.x;
    int c0 = (t & 15)*8;
    int xi = t >> 4;
    float wreg[9][8];
    #pragma unroll
    for(int k=0;k<9;k++){
        float4 a = *(const float4*)(w1 + k*C_ + c0);
        float4 bq = *(const float4*)(w1 + k*C_ + c0 + 4);
        wreg[k][0]=a.x; wreg[k][1]=a.y; wreg[k][2]=a.z; wreg[k][3]=a.w;
        wreg[k][4]=bq.x; wreg[k][5]=bq.y; wreg[k][6]=bq.z; wreg[k][7]=bq.w;
    }
    const ushort* vb = vinp + (long)b*NPIX*C_;
    ushort* cb = c1 + (long)b*NPIX*C_;
    for(int p=0;p<16;p++){
        int xx = p*16 + xi;
        float s[8] = {0,0,0,0,0,0,0,0};
        #pragma unroll
        for(int ky=0;ky<3;ky++){
            int yy = y + ky - 1;
            if(yy < 0 || yy >= H_) continue;
            #pragma unroll
            for(int kx=0;kx<3;kx++){
                int xw = xx + kx - 1;
                if(xw < 0 || xw >= W_) continue;
                uint4 vv = *(const uint4*)(vb + ((long)yy*W_ + xw)*C_ + c0);
                const ushort* pv = (const ushort*)&vv;
                #pragma unroll
                for(int i=0;i<8;i++) s[i] += bf2f(pv[i]) * wreg[ky*3+kx][i];
            }
        }
        uint4 o;
        uint op[4];
        #pragma unroll
        for(int i2=0;i2<4;i2++){
            float va = s[i2*2],   ga = 0.5f*va*(1.0f+erff(va*0.70710678118654752f));
            float vb2 = s[i2*2+1], gb = 0.5f*vb2*(1.0f+erff(vb2*0.70710678118654752f));
            op[i2] = (uint)f2bf(ga) | ((uint)f2bf(gb)<<16);
        }
        o.x=op[0]; o.y=op[1]; o.z=op[2]; o.w=op[3];
        *(uint4*)(cb + ((long)y*W_ + xx)*C_ + c0) = o;
    }
}

// ---------------------------------------------------------------------------
// K4b: out = (v_inp .* ilf) @ WeffT_b + bp
// ---------------------------------------------------------------------------
__global__ __launch_bounds__(256) void k4b_x1(const ushort* __restrict__ vinp, const float* __restrict__ ilf,
                                              const ushort* __restrict__ WeffT, const float* __restrict__ bp,
                                              float* __restrict__ out){
    __shared__ __align__(16) char smv[128*256];
    __shared__ __align__(16) char smw[128*256];
    int blk = blockIdx.x;
    int b = blk >> 9; int tileI = blk & 511;
    long rowbase = (long)b*NPIX + (long)tileI*128;
    int t = threadIdx.x, lane=t&63, w=t>>6;
    int m0=(w>>1)*64, n0=(w&1)*64;
    {
        const ushort* wp = WeffT + b*C_*C_;
        #pragma unroll
        for(int p=0;p<8;p++){
            int idx = p*256 + t;
            int cR = idx >> 4; int ub = idx & 15;
            uint4 d = *(const uint4*)(wp + cR*C_ + ub*8);
            *(uint4*)(smw + cR*256 + ((ub*16) ^ (swz3(cR)<<4))) = d;
        }
    }
    {
        const ushort* vp = vinp + rowbase*C_;
        const float*  ip = ilf + rowbase*C_;
        #pragma unroll
        for(int p=0;p<8;p++){
            int r = p*16 + (t>>4);
            int c0 = (t&15)*8;
            uint4 vv = *(const uint4*)(vp + r*C_ + c0);
            const ushort* pv = (const ushort*)&vv;
            float4 i0 = *(const float4*)(ip + r*C_ + c0);
            float4 i1 = *(const float4*)(ip + r*C_ + c0 + 4);
            uint4 pk;
            pk.x = (uint)f2bf(bf2f(pv[0])*i0.x) | ((uint)f2bf(bf2f(pv[1])*i0.y)<<16);
            pk.y = (uint)f2bf(bf2f(pv[2])*i0.z) | ((uint)f2bf(bf2f(pv[3])*i0.w)<<16);
            pk.z = (uint)f2bf(bf2f(pv[4])*i1.x) | ((uint)f2bf(bf2f(pv[5])*i1.y)<<16);
            pk.w = (uint)f2bf(bf2f(pv[6])*i1.z) | ((uint)f2bf(bf2f(pv[7])*i1.w)<<16);
            *(uint4*)(smv + r*256 + ((2*c0) ^ (swz3(r)<<4))) = pk;
        }
    }
    __syncthreads();

    f32x4 acc[4][4];
    #pragma unroll
    for(int i=0;i<4;i++)
        #pragma unroll
        for(int j=0;j<4;j++) acc[i][j] = {0.f,0.f,0.f,0.f};

    #pragma unroll
    for(int kk=0;kk<4;kk++){
        int kb = kk*32 + (lane>>4)*8;
        bf16x8 A[4], Bf[4];
        #pragma unroll
        for(int i=0;i<4;i++){
            int r = m0 + i*16 + (lane&15);
            A[i] = *(const bf16x8*)(smv + r*256 + ((2*kb) ^ (swz3(r)<<4)));
        }
        #pragma unroll
        for(int j=0;j<4;j++){
            int o = n0 + j*16 + (lane&15);
            Bf[j] = *(const bf16x8*)(smw + o*256 + ((2*kb) ^ (swz3(o)<<4)));
        }
        #pragma unroll
        for(int i=0;i<4;i++)
            #pragma unroll
            for(int j=0;j<4;j++)
                acc[i][j] = __builtin_amdgcn_mfma_f32_16x16x32_bf16(A[i], Bf[j], acc[i][j], 0,0,0);
    }
    float* op = out + rowbase*C_;
    int rq = (lane>>4)*4, cc = lane&15;
    #pragma unroll
    for(int j=0;j<4;j++){
        int col = n0 + j*16 + cc;
        float bias = bp[col];
        #pragma unroll
        for(int i=0;i<4;i++)
            #pragma unroll
            for(int rg=0;rg<4;rg++){
                int row = m0 + i*16 + rq + rg;
                op[row*C_ + col] = acc[i][j][rg] + bias;
            }
    }
}

// ---------------------------------------------------------------------------
// K4c: out += dwconv3x3(c1, w2)
// ---------------------------------------------------------------------------
__global__ __launch_bounds__(256) void k4c_conv2(const ushort* __restrict__ c1, const float* __restrict__ w2,
                                                 float* __restrict__ out){
    int blk = blockIdx.x;
    int b = blk >> 8; int y = blk & 255;
    int t = threadIdx.x;
    int c0 = (t & 15)*8;
    int xi = t >> 4;
    float wreg[9][8];
    #pragma unroll
    for(int k=0;k<9;k++){
        float4 a = *(const float4*)(w2 + k*C_ + c0);
        float4 bq = *(const float4*)(w2 + k*C_ + c0 + 4);
        wreg[k][0]=a.x; wreg[k][1]=a.y; wreg[k][2]=a.z; wreg[k][3]=a.w;
        wreg[k][4]=bq.x; wreg[k][5]=bq.y; wreg[k][6]=bq.z; wreg[k][7]=bq.w;
    }
    const ushort* cb = c1 + (long)b*NPIX*C_;
    float* ob = out + (long)b*NPIX*C_;
    for(int p=0;p<16;p++){
        int xx = p*16 + xi;
        float s[8] = {0,0,0,0,0,0,0,0};
        #pragma unroll
        for(int ky=0;ky<3;ky++){
            int yy = y + ky - 1;
            if(yy < 0 || yy >= H_) continue;
            #pragma unroll
            for(int kx=0;kx<3;kx++){
                int xw = xx + kx - 1;
                if(xw < 0 || xw >= W_) continue;
                uint4 vv = *(const uint4*)(cb + ((long)yy*W_ + xw)*C_ + c0);
                const ushort* pv = (const ushort*)&vv;
                #pragma unroll
                for(int i=0;i<8;i++) s[i] += bf2f(pv[i]) * wreg[ky*3+kx][i];
            }
        }
        long off = ((long)y*W_ + xx)*C_ + c0;
        float4 o0 = *(const float4*)(ob + off);
        float4 o1 = *(const float4*)(ob + off + 4);
        o0.x += s[0]; o0.y += s[1]; o0.z += s[2]; o0.w += s[3];
        o1.x += s[4]; o1.y += s[5]; o1.z += s[6]; o1.w += s[7];
        *(float4*)(ob + off) = o0;
        *(float4*)(ob + off + 4) = o1;
    }
}

extern "C" void kernel_launch(void* const* d_in, const int* in_sizes, int n_in,
                              void* d_out, int out_size, void* d_ws, size_t ws_size,
                              hipStream_t stream){
    (void)in_sizes; (void)n_in; (void)out_size; (void)ws_size;
    const float* x    = (const float*)d_in[0];
    const float* ilf  = (const float*)d_in[1];
    const float* Wq   = (const float*)d_in[2];
    const float* Wk   = (const float*)d_in[3];
    const float* Wv   = (const float*)d_in[4];
    const float* rsc  = (const float*)d_in[5];
    const float* Wp   = (const float*)d_in[6];
    const float* bp   = (const float*)d_in[7];
    const float* w1   = (const float*)d_in[8];
    const float* w2   = (const float*)d_in[9];
    float* out = (float*)d_out;
    char* ws = (char*)d_ws;

    ushort* vinp  = (ushort*)ws;                       // 64 MiB
    ushort* c1    = (ushort*)(ws + 67108864);          // 64 MiB (written by k4a)
    float*  TQ    = (float*)(ws + 67108864);           // 256 KiB, aliases c1 (dead until k4a)
    float*  S     = (float*)(ws + 134217728);          // 256 KiB  [zeroed]
    float*  nrm   = (float*)(ws + 134479872);          // 4 KiB    [zeroed]
    ushort* WeffT = (ushort*)(ws + 134483968);         // 128 KiB

    hipMemsetAsync(S, 0, 262144 + 4096, stream);
    hipLaunchKernelGGL(k1_syrk,  dim3(512),  dim3(256), 0, stream, x, S);
    hipLaunchKernelGGL(k2_vinp,  dim3(2048), dim3(256), 0, stream, x, Wv, vinp);
    hipLaunchKernelGGL(k3a,      dim3(512),  dim3(256), 0, stream, S, Wq, Wk, TQ, nrm);
    hipLaunchKernelGGL(k3b,      dim3(16),   dim3(256), 0, stream, TQ, Wk, rsc, Wp, nrm, WeffT);
    hipLaunchKernelGGL(k4a_conv1,dim3(1024), dim3(256), 0, stream, vinp, w1, c1);
    hipLaunchKernelGGL(k4b_x1,   dim3(2048), dim3(256), 0, stream, vinp, ilf, WeffT, bp, out);
    hipLaunchKernelGGL(k4c_conv2,dim3(1024), dim3(256), 0, stream, c1, w2, out);
}